// Round 1
// baseline (117.120 us; speedup 1.0000x reference)
//
#include <hip/hip_runtime.h>

// out[b, p] = sum_s prob[b,s] * param[p, idx[b,s]]
//   param: (512*2048, 64) fp32  = 256 MiB
//   sel:   (64, 4) int32, prob: (64, 4) fp32
//   out:   (64, 512*2048) fp32  = 256 MiB
// Memory-bound streaming: floor ~= 512 MiB / 6.3 TB/s ~= 81 us.

#define NPOS   (512 * 2048)   // positions
#define NBANK  64
#define NBATCH 64
#define NSEL   4
#define TILE   256            // positions per workgroup
#define STRIDE 65             // padded words per position row (bank-conflict-free)

__global__ __launch_bounds__(256, 2) void vparam_kernel(
    const float* __restrict__ param,
    const int*   __restrict__ sel,
    const float* __restrict__ prob,
    float*       __restrict__ out)
{
    __shared__ float lds[TILE * STRIDE];   // 66,560 B -> 2 blocks/CU

    const int tid       = threadIdx.x;
    const int tile_base = blockIdx.x * TILE;

    // ---- Stage: contiguous 64 KiB tile -> padded LDS rows (coalesced f4 loads) ----
    const float4* g4 = (const float4*)(param + (size_t)tile_base * NBANK);
    #pragma unroll
    for (int i = 0; i < 16; ++i) {
        float4 v = g4[i * 256 + tid];              // wave: 64 contiguous float4 = 1 KiB
        int pos = i * 16 + (tid >> 4);
        int k   = (tid & 15) * 4;
        float* dst = &lds[pos * STRIDE + k];
        // scalar writes: bank = (pos + k + j) mod 32 -> 2 lanes/bank -> free
        dst[0] = v.x; dst[1] = v.y; dst[2] = v.z; dst[3] = v.w;
    }
    __syncthreads();

    // ---- Gather + weighted sum: thread owns one position row in LDS ----
    const float* row = &lds[tid * STRIDE]; // read bank = (lane + idx) mod 32 -> free
    const int p = tile_base + tid;
    const int4*   sel4  = (const int4*)sel;    // uniform addr -> s_load_dwordx4
    const float4* prob4 = (const float4*)prob;

    #pragma unroll 4
    for (int b = 0; b < NBATCH; ++b) {
        int4   iv = sel4[b];
        float4 wv = prob4[b];
        float acc =       row[iv.x] * wv.x;
        acc = fmaf(row[iv.y], wv.y, acc);
        acc = fmaf(row[iv.z], wv.z, acc);
        acc = fmaf(row[iv.w], wv.w, acc);
        out[b * NPOS + p] = acc;               // wave: 256 B contiguous store
    }
}

extern "C" void kernel_launch(void* const* d_in, const int* in_sizes, int n_in,
                              void* d_out, int out_size, void* d_ws, size_t ws_size,
                              hipStream_t stream) {
    const float* param = (const float*)d_in[0];
    const int*   sel   = (const int*)d_in[1];
    const float* prob  = (const float*)d_in[2];
    float*       out   = (float*)d_out;

    dim3 grid(NPOS / TILE);   // 4096 blocks, exact
    vparam_kernel<<<grid, 256, 0, stream>>>(param, sel, prob, out);
}

// Round 2
// 98.545 us; speedup vs baseline: 1.1885x; 1.1885x over previous
//
#include <hip/hip_runtime.h>

// out[b, p] = sum_s prob[b,s] * param[p, idx[b,s]]
//   param: (512*2048, 64) fp32 = 256 MiB ; out: (64, 512*2048) fp32 = 256 MiB
// Streaming floor ~= 512 MiB / 6.3 TB/s ~= 81 us.
//
// LDS layout: transposed (bank-major) + XOR swizzle:
//   word(k, p) at k*TILE + (p ^ (k & 28))
// - staging writes: bank = (p ^ 4*(lane&7)) & 31 -> exactly 2 lanes/bank (free)
// - gather reads: ds_read_b128, wave covers a full (permuted) contiguous 1 KiB
//   bank-row -> conflict-free; one b128 = 4 consecutive positions.

#define NPOS   (512 * 2048)
#define NBANK  64
#define NBATCH 64
#define TILE   256

typedef float  f32x4 __attribute__((ext_vector_type(4)));
typedef int    i32x4 __attribute__((ext_vector_type(4)));

__global__ __launch_bounds__(256, 2) void vparam_kernel(
    const float* __restrict__ param,
    const int*   __restrict__ sel,
    const float* __restrict__ prob,
    float*       __restrict__ out)
{
    __shared__ float lds[NBANK * TILE];   // 64 KiB -> 2 blocks/CU

    const int tid       = threadIdx.x;
    const int tile_base = blockIdx.x * TILE;

    // ---- Stage: global (position-major) -> LDS (bank-major, swizzled) ----
    const f32x4* g4 = (const f32x4*)(param + (size_t)tile_base * NBANK);
    #pragma unroll
    for (int i = 0; i < 16; ++i) {
        f32x4 v = __builtin_nontemporal_load(&g4[i * 256 + tid]); // 1 KiB/wave, coalesced
        int p  = i * 16 + (tid >> 4);       // position within tile
        int k0 = (tid & 15) * 4;            // first of 4 consecutive banks
        #pragma unroll
        for (int j = 0; j < 4; ++j) {
            int k = k0 + j;
            lds[k * TILE + (p ^ (k & 28))] = v[j];   // 2-way banks -> free
        }
    }
    __syncthreads();

    // ---- Gather: wave-uniform banks, b128 reads, float4 nt stores ----
    const int wave = tid >> 6;
    const int lane = tid & 63;
    const int pw   = lane * 4;              // lane's 4 positions (word offset)
    const i32x4* sel4  = (const i32x4*)sel;
    const f32x4* prob4 = (const f32x4*)prob;

    #pragma unroll 4
    for (int j = 0; j < 16; ++j) {
        int b = __builtin_amdgcn_readfirstlane(wave * 16 + j);  // -> s_load
        i32x4 iv = sel4[b];
        f32x4 wv = prob4[b];
        const f32x4 a0 = *(const f32x4*)&lds[iv.x * TILE + (pw ^ (iv.x & 28))];
        const f32x4 a1 = *(const f32x4*)&lds[iv.y * TILE + (pw ^ (iv.y & 28))];
        const f32x4 a2 = *(const f32x4*)&lds[iv.z * TILE + (pw ^ (iv.z & 28))];
        const f32x4 a3 = *(const f32x4*)&lds[iv.w * TILE + (pw ^ (iv.w & 28))];
        f32x4 acc = a0 * wv.x + a1 * wv.y + a2 * wv.z + a3 * wv.w;
        f32x4* o = (f32x4*)(out + (size_t)b * NPOS + tile_base);
        __builtin_nontemporal_store(acc, &o[lane]);  // 1 KiB/wave, coalesced
    }
}

extern "C" void kernel_launch(void* const* d_in, const int* in_sizes, int n_in,
                              void* d_out, int out_size, void* d_ws, size_t ws_size,
                              hipStream_t stream) {
    const float* param = (const float*)d_in[0];
    const int*   sel   = (const int*)d_in[1];
    const float* prob  = (const float*)d_in[2];
    float*       out   = (float*)d_out;

    dim3 grid(NPOS / TILE);   // 4096 blocks
    vparam_kernel<<<grid, 256, 0, stream>>>(param, sel, prob, out);
}

// Round 3
// 96.252 us; speedup vs baseline: 1.2168x; 1.0238x over previous
//
#include <hip/hip_runtime.h>

// out[b, p] = sum_s prob[b,s] * param[p, idx[b,s]]
//   param: (512*2048, 64) fp32 = 256 MiB ; out: (64, 512*2048) fp32 = 256 MiB
// Streaming floor ~= 537 MB / 6.29 TB/s (measured R+W copy ceiling) ~= 85 us.
//
// LDS layout: transposed (bank-major) + XOR swizzle:
//   word(k, p) at k*TILE + (p ^ (k & 28))
// - staging writes: bank = ((pbase+q) ^ 4*(lane&7)) & 31 -> exactly 2 lanes/bank (free)
// - gather reads: ds_read_b128, wave covers a full (permuted) contiguous 1 KiB
//   bank-row -> conflict-free; one b128 = 4 consecutive positions.
// Round 3 change: 512-thread blocks (same 64 KiB LDS, still 2 blocks/CU)
// -> 4 waves/SIMD instead of 2, for latency hiding / phase overlap.

#define NPOS   (512 * 2048)
#define NBANK  64
#define NBATCH 64
#define TILE   256
#define BLK    512

typedef float  f32x4 __attribute__((ext_vector_type(4)));
typedef int    i32x4 __attribute__((ext_vector_type(4)));

__global__ __launch_bounds__(BLK, 4) void vparam_kernel(
    const float* __restrict__ param,
    const int*   __restrict__ sel,
    const float* __restrict__ prob,
    float*       __restrict__ out)
{
    __shared__ float lds[NBANK * TILE];   // 64 KiB -> 2 blocks/CU (128/160 KiB)

    const int tid       = threadIdx.x;
    const int tile_base = blockIdx.x * TILE;

    // ---- Stage: global (position-major) -> LDS (bank-major, swizzled) ----
    const f32x4* g4 = (const f32x4*)(param + (size_t)tile_base * NBANK);
    #pragma unroll
    for (int i = 0; i < 8; ++i) {
        f32x4 v = __builtin_nontemporal_load(&g4[i * BLK + tid]); // 1 KiB/wave, coalesced
        int p  = i * 32 + (tid >> 4);       // position within tile
        int k0 = (tid & 15) * 4;            // first of 4 consecutive banks
        #pragma unroll
        for (int j = 0; j < 4; ++j) {
            int k = k0 + j;
            lds[k * TILE + (p ^ (k & 28))] = v[j];   // 2 lanes/bank -> free
        }
    }
    __syncthreads();

    // ---- Gather: wave-uniform banks, b128 reads, float4 nt stores ----
    const int wave = tid >> 6;               // 0..7
    const int lane = tid & 63;
    const int pw   = lane * 4;               // lane's 4 positions (word offset)
    const i32x4* sel4  = (const i32x4*)sel;
    const f32x4* prob4 = (const f32x4*)prob;

    #pragma unroll
    for (int j = 0; j < 8; ++j) {
        int b = __builtin_amdgcn_readfirstlane(wave * 8 + j);   // -> s_load
        i32x4 iv = sel4[b];
        f32x4 wv = prob4[b];
        const f32x4 a0 = *(const f32x4*)&lds[iv.x * TILE + (pw ^ (iv.x & 28))];
        const f32x4 a1 = *(const f32x4*)&lds[iv.y * TILE + (pw ^ (iv.y & 28))];
        const f32x4 a2 = *(const f32x4*)&lds[iv.z * TILE + (pw ^ (iv.z & 28))];
        const f32x4 a3 = *(const f32x4*)&lds[iv.w * TILE + (pw ^ (iv.w & 28))];
        f32x4 acc = a0 * wv.x + a1 * wv.y + a2 * wv.z + a3 * wv.w;
        f32x4* o = (f32x4*)(out + (size_t)b * NPOS + tile_base);
        __builtin_nontemporal_store(acc, &o[lane]);  // 1 KiB/wave, coalesced
    }
}

extern "C" void kernel_launch(void* const* d_in, const int* in_sizes, int n_in,
                              void* d_out, int out_size, void* d_ws, size_t ws_size,
                              hipStream_t stream) {
    const float* param = (const float*)d_in[0];
    const int*   sel   = (const int*)d_in[1];
    const float* prob  = (const float*)d_in[2];
    float*       out   = (float*)d_out;

    dim3 grid(NPOS / TILE);   // 4096 blocks
    vparam_kernel<<<grid, BLK, 0, stream>>>(param, sel, prob, out);
}